// Round 15
// baseline (102.088 us; speedup 1.0000x reference)
//
#include <hip/hip_runtime.h>
#include <math.h>

#define NPOS   2048
#define NANCH  4096          // pos + neg
#define CIN    1280
#define HID    128
#define W_     28
#define HW_    784           // 28*28
#define AHW    7056          // 9*784
#define FB     (CIN*HW_)     // floats per batch image
#define SLAB   4             // channels per LDS slab
#define SLABF  (SLAB*HW_)    // 3136 floats per slab
#define KSEL   16
#define KCH    (CIN/KSEL)    // 80 channels per block
#define NSLAB  (KCH/SLAB)    // 20

__device__ __forceinline__ float sigmoidf_(float x) {
    return 1.0f / (1.0f + __expf(-x));
}
__device__ __forceinline__ unsigned short f2bf(float x) {   // RNE f32->bf16
    unsigned int u = __float_as_uint(x);
    return (unsigned short)((u + 0x7fffu + ((u >> 16) & 1u)) >> 16);
}
__device__ __forceinline__ float bf_lo(unsigned int w) { return __uint_as_float(w << 16); }
__device__ __forceinline__ float bf_hi(unsigned int w) { return __uint_as_float(w & 0xffff0000u); }

typedef __attribute__((address_space(3))) float lds_f;
typedef __attribute__((address_space(1))) const float glb_f;
__device__ __forceinline__ void gload16(const float* g, float* l) {
    __builtin_amdgcn_global_load_lds((glb_f*)g, (lds_f*)l, 16, 0, 0);
}

#define SCHED_FENCE() __builtin_amdgcn_sched_barrier(0)
#define WAIT_VM4()  asm volatile("s_waitcnt vmcnt(4)" ::: "memory")
#define WAIT_VM3()  asm volatile("s_waitcnt vmcnt(3)" ::: "memory")
#define WAIT_VM0()  asm volatile("s_waitcnt vmcnt(0)" ::: "memory")
#define WAIT_LGKM0() asm volatile("s_waitcnt lgkmcnt(0)" ::: "memory")

// ---------------------------------------------------------------------------
// K1: fused gather+GEMM1 — r10 structure + XCD-aware block swizzle.
// 1-D grid of 1024; l = r + 8*ks + 128*q  (bijective; nwg%8==0) so all 16
// k-chunk blocks of image b = 8q+r share l%8 -> same XCD -> the image's
// 4 MB is resident in ONE XCD L2 and reused 16x (was duplicated across up
// to 8 XCDs -> L3->L2 path paid ~8x). Body identical to r10: SLAB=4 slabs,
// counted-vmcnt 2-deep pipeline (w0: 3 VMEM/slab, w1-3: 4), static acc
// indices, 4 blocks/CU. nb<=128 assumed (P ~ 1e-9 for this fixed input).
// ---------------------------------------------------------------------------
__global__ __launch_bounds__(256, 4) void k_fused(
    const float* __restrict__ F, const float* __restrict__ W1,
    const int* __restrict__ posi, const int* __restrict__ negi,
    unsigned short* __restrict__ Hp)
{
    __shared__ float Pl[2][SLABF];     // 25088 B
    __shared__ float Wl[2][520];       //  4160 B (two 260-pitch halves)
    __shared__ int   pkl[128];
    __shared__ int   nbL;

    const int l    = blockIdx.x;       // XCD swizzle decode
    const int b    = 8 * (l >> 7) + (l & 7);
    const int ks   = (l >> 3) & 15;
    const int t    = threadIdx.x;
    const int w    = t >> 6;
    const int lane = t & 63;

    if (t == 0) nbL = 0;
    if (t < 128) pkl[t] = 0;
    __syncthreads();                    // LDS init visible (no DMA yet)

    const int kb0 = ks * KCH;

    auto issue = [&](int sl2, int buf) {
        const int kb = kb0 + sl2 * SLAB;
        const float* srcP = F + (size_t)b * FB + (size_t)kb * HW_;
        float* dstP = &Pl[buf][0];
#pragma unroll
        for (int i = 0; i < 3; ++i) {   // 12 chunks of 256 floats
            const int c = w + 4 * i;
            gload16(srcP + c * 256 + lane * 4, dstP + c * 256);
        }
        if (w == 3) {                   // tail 64 floats
            if (lane < 16) gload16(srcP + 3072 + lane * 4, dstP + 3072);
        }
        if (w == 1) gload16(W1 + (size_t)lane * CIN + kb, &Wl[buf][0]);
        if (w == 2) gload16(W1 + (size_t)(64 + lane) * CIN + kb, &Wl[buf][260]);
    };
    // per-wave VMEM count per slab: w0=3, w1..3=4

    // ---- issue slabs 0,1 FIRST; bucket scan overlaps the DMA
    issue(0, 0);
    issue(1, 1);

#pragma unroll
    for (int r = 0; r < 16; ++r) {
        const int g    = r * 256 + t;
        const int aidx = (g < NPOS) ? posi[g] : negi[g - NPOS];
        const int bb   = aidx / AHW;
        if (bb == b) {
            const int hw   = (aidx - bb * AHW) % HW_;
            const int slot = atomicAdd(&nbL, 1);
            if (slot < 128) pkl[slot] = (g << 10) | hw;
        }
    }
    WAIT_LGKM0();                       // own LDS atomics drained
    SCHED_FENCE();
    __builtin_amdgcn_s_barrier();       // bucket results visible
    SCHED_FENCE();

    const int  nb   = nbL;
    const bool wact = (w * 32) < nb;    // wave-uniform
    const int  og   = lane >> 3;        // 8 out-groups of 16 outs
    const int  al   = w * 32 + (lane & 7) * 4;  // first of this lane's 4 anchors
    int hwr[4], gr[4];
#pragma unroll
    for (int ai = 0; ai < 4; ++ai) {
        const int a  = al + ai;         // <= 127
        const int pk = pkl[a];
        hwr[ai] = pk & 1023;
        gr[ai]  = (a < nb) ? (pk >> 10) : -1;
    }
    const int WB = (og < 4) ? og * 64 : 260 + (og - 4) * 64;

    float acc[4][16];
#pragma unroll
    for (int ai = 0; ai < 4; ++ai)
#pragma unroll
        for (int m = 0; m < 16; ++m) acc[ai][m] = 0.0f;

    if (w == 0) { WAIT_VM3(); } else { WAIT_VM4(); }   // slab 0 arrived (own)
    SCHED_FENCE();
    __builtin_amdgcn_s_barrier();       // all waves' slab-0 loads arrived
    SCHED_FENCE();

    for (int sl = 0; sl < NSLAB; ++sl) {
        const int cur = sl & 1;
        if (wact) {
            float ga[4][4];
#pragma unroll
            for (int ai = 0; ai < 4; ++ai)
#pragma unroll
                for (int c = 0; c < 4; ++c)
                    ga[ai][c] = Pl[cur][c * HW_ + hwr[ai]];
#pragma unroll
            for (int m = 0; m < 16; ++m) {
                const float4 wv = *(const float4*)&Wl[cur][WB + 4 * m];
#pragma unroll
                for (int ai = 0; ai < 4; ++ai) {
                    float v = acc[ai][m];
                    v = fmaf(ga[ai][0], wv.x, v);
                    v = fmaf(ga[ai][1], wv.y, v);
                    v = fmaf(ga[ai][2], wv.z, v);
                    v = fmaf(ga[ai][3], wv.w, v);
                    acc[ai][m] = v;
                }
            }
        }
        if (sl + 1 < NSLAB) {
            WAIT_LGKM0();               // my reads of Pl[cur] complete
            SCHED_FENCE();
            __builtin_amdgcn_s_barrier();   // B1: everyone done with cur
            SCHED_FENCE();
            if (sl + 2 < NSLAB) {
                issue(sl + 2, cur);
                SCHED_FENCE();
                if (w == 0) { WAIT_VM3(); } else { WAIT_VM4(); }
            } else {
                WAIT_VM0();
            }
            SCHED_FENCE();
            __builtin_amdgcn_s_barrier();   // B2: slab sl+1 visible
            SCHED_FENCE();
        }
    }

    // ---- store bf16 partials: 4 anchors x 16 outs per lane (static pack)
    if (wact) {
#pragma unroll
        for (int ai = 0; ai < 4; ++ai) {
            const int g = gr[ai];
            if (g >= 0) {
                unsigned short* dst =
                    Hp + ((size_t)ks * NANCH + g) * HID + og * 16;
                unsigned u[8];
#pragma unroll
                for (int q = 0; q < 8; ++q)
                    u[q] = (unsigned)f2bf(acc[ai][2 * q]) |
                           ((unsigned)f2bf(acc[ai][2 * q + 1]) << 16);
                *(uint4*)(dst)     = make_uint4(u[0], u[1], u[2], u[3]);
                *(uint4*)(dst + 8) = make_uint4(u[4], u[5], u[6], u[7]);
            }
        }
    }
}

// ---------------------------------------------------------------------------
// K2: wave-per-anchor loss. Sums KSEL bf16 partials + bias + leaky inline,
// then layer-2 rows + IoU/argmax + losses. Plain store to contrib.
// ---------------------------------------------------------------------------
__global__ __launch_bounds__(256) void k_loss(
    const unsigned short* __restrict__ Hp, const float* __restrict__ b1,
    const float* __restrict__ W2, const float* __restrict__ b2,
    const int* __restrict__ posi, const int* __restrict__ negi,
    const float* __restrict__ bboxes, const float* __restrict__ anc,
    float* __restrict__ contrib)
{
    const int wid  = threadIdx.x >> 6;
    const int lane = threadIdx.x & 63;
    const int g    = blockIdx.x * 4 + wid;

    const int aidx = (g < NPOS) ? posi[g] : negi[g - NPOS];
    const int b   = aidx / AHW;
    const int rem = aidx - b * AHW;
    const int a   = rem / HW_;
    const int hw  = rem - a * HW_;
    const int hh  = hw / W_;
    const int ww  = hw - hh * W_;

    float hx = b1[2 * lane], hy = b1[2 * lane + 1];
#pragma unroll
    for (int ks = 0; ks < KSEL; ++ks) {
        const unsigned raw =
            *(const unsigned*)&Hp[((size_t)ks * NANCH + g) * HID + 2 * lane];
        hx += bf_lo(raw);
        hy += bf_hi(raw);
    }
    hx = (hx > 0.0f) ? hx : 0.01f * hx;
    hy = (hy > 0.0f) ? hy : 0.01f * hy;

    if (g < NPOS) {
        float outv[25];
#pragma unroll
        for (int j = 0; j < 25; ++j) {
            const int row = (j < 5) ? (5 * a + j) : (40 + j);
            const float2 w = *(const float2*)&W2[(size_t)row * HID + 2 * lane];
            float v = fmaf(w.x, hx, w.y * hy);
#pragma unroll
            for (int off = 1; off < 64; off <<= 1) v += __shfl_xor(v, off, 64);
            outv[j] = v + b2[row];
        }

        const float wa = anc[2 * a], ha = anc[2 * a + 1];
        const float cx = ww + 0.5f, cy = hh + 0.5f;
        const float ax1 = cx - 0.5f * wa, ay1 = cy - 0.5f * ha;
        const float ax2 = cx + 0.5f * wa, ay2 = cy + 0.5f * ha;
        const float areap = wa * ha;

        float v; int vi = lane;
        if (lane < 40) {
            const float* bb = &bboxes[(size_t)(b * 40 + lane) * 5];
            const float bx1 = bb[0], by1 = bb[1], bx2 = bb[2], by2 = bb[3];
            const float areab = (bx2 - bx1) * (by2 - by1);
            const float ix1 = fmaxf(ax1, bx1), iy1 = fmaxf(ay1, by1);
            const float ix2 = fminf(ax2, bx2), iy2 = fminf(ay2, by2);
            const float inter = fmaxf(ix2 - ix1, 0.0f) * fmaxf(iy2 - iy1, 0.0f);
            v = inter / (areap + areab - inter);
        } else {
            v = -1.0f;
        }
#pragma unroll
        for (int off = 1; off < 64; off <<= 1) {
            const float ov = __shfl_xor(v, off, 64);
            const int   oi = __shfl_xor(vi, off, 64);
            if (ov > v || (ov == v && oi < vi)) { v = ov; vi = oi; }
        }
        const int m = vi;

        const float* gt = &bboxes[(size_t)(b * 40 + m) * 5];
        const float gx1 = gt[0], gy1 = gt[1], gx2 = gt[2], gy2 = gt[3];
        const int   gcls = (int)gt[4];
        const float xb = 0.5f * (gx1 + gx2), yb = 0.5f * (gy1 + gy2);
        const float wb = gx2 - gx1, hb = gy2 - gy1;
        const float go0 = xb - cx, go1 = yb - cy;
        const float go2 = __logf(wb / wa), go3 = __logf(hb / ha);

        const float o0 = sigmoidf_(outv[1]) - 0.5f;
        const float o1 = sigmoidf_(outv[2]) - 0.5f;
        const float o2 = outv[3], o3 = outv[4];
        const float reg = (o0 - go0) * (o0 - go0) + (o1 - go1) * (o1 - go1) +
                          (o2 - go2) * (o2 - go2) + (o3 - go3) * (o3 - go3);

        const float conf = sigmoidf_(outv[0]);
        const float conft = (conf - 1.0f) * (conf - 1.0f);

        float mx = outv[5];
#pragma unroll
        for (int c = 1; c < 20; ++c) mx = fmaxf(mx, outv[5 + c]);
        float se = 0.0f;
#pragma unroll
        for (int c = 0; c < 20; ++c) se += __expf(outv[5 + c] - mx);
        float lgt = 0.0f;
#pragma unroll
        for (int c = 0; c < 20; ++c) if (c == gcls) lgt = outv[5 + c];
        const float clst = -(lgt - mx - __logf(se));

        if (lane == 0)
            contrib[g] = conft * (1.0f / 4096.0f) + reg * (1.0f / 2048.0f) +
                         clst * (1.0f / 2048.0f);
    } else {
        const int row = 5 * a;
        const float2 w = *(const float2*)&W2[(size_t)row * HID + 2 * lane];
        float v = fmaf(w.x, hx, w.y * hy);
#pragma unroll
        for (int off = 1; off < 64; off <<= 1) v += __shfl_xor(v, off, 64);
        const float conf = sigmoidf_(v + b2[row]);
        if (lane == 0) contrib[g] = conf * conf * (1.0f / 4096.0f);
    }
}

// ---------------------------------------------------------------------------
// K3: final reduction (deterministic)
// ---------------------------------------------------------------------------
__global__ __launch_bounds__(256) void k_final(const float* __restrict__ contrib,
                                               float* __restrict__ out)
{
    __shared__ float red[256];
    const int t = threadIdx.x;
    float s = 0.0f;
    for (int i = t; i < NANCH; i += 256) s += contrib[i];
    red[t] = s;
    __syncthreads();
    for (int st = 128; st > 0; st >>= 1) {
        if (t < st) red[t] += red[t + st];
        __syncthreads();
    }
    if (t == 0) out[0] = red[0];
}

extern "C" void kernel_launch(void* const* d_in, const int* in_sizes, int n_in,
                              void* d_out, int out_size, void* d_ws, size_t ws_size,
                              hipStream_t stream)
{
    const float* F      = (const float*)d_in[0];
    const float* bboxes = (const float*)d_in[1];
    const int*   posi   = (const int*)d_in[2];
    const int*   negi   = (const int*)d_in[3];
    const float* W1     = (const float*)d_in[4];
    const float* b1     = (const float*)d_in[5];
    const float* W2     = (const float*)d_in[6];
    const float* b2     = (const float*)d_in[7];
    const float* anc    = (const float*)d_in[8];
    float* out = (float*)d_out;

    char* ws = (char*)d_ws;
    unsigned short* Hp      = (unsigned short*)ws;
    float*          contrib = (float*)(ws + (size_t)KSEL * NANCH * HID * 2);

    k_fused<<<64 * KSEL, 256, 0, stream>>>(F, W1, posi, negi, Hp);
    k_loss<<<NANCH / 4, 256, 0, stream>>>(Hp, b1, W2, b2, posi, negi,
                                          bboxes, anc, contrib);
    k_final<<<1, 256, 0, stream>>>(contrib, out);
    (void)in_sizes; (void)n_in; (void)out_size; (void)ws_size;
}

// Round 16
// 84.059 us; speedup vs baseline: 1.2145x; 1.2145x over previous
//
#include <hip/hip_runtime.h>
#include <math.h>

#define NPOS   2048
#define NANCH  4096          // pos + neg
#define CIN    1280
#define HID    128
#define W_     28
#define HW_    784           // 28*28
#define AHW    7056          // 9*784
#define FB     (CIN*HW_)     // floats per batch image
#define SLAB   4             // channels per LDS slab
#define SLABF  (SLAB*HW_)    // 3136 floats per slab
#define KSEL   16
#define KCH    (CIN/KSEL)    // 80 channels per block
#define NSLAB  (KCH/SLAB)    // 20

__device__ __forceinline__ float sigmoidf_(float x) {
    return 1.0f / (1.0f + __expf(-x));
}
__device__ __forceinline__ unsigned short f2bf(float x) {   // RNE f32->bf16
    unsigned int u = __float_as_uint(x);
    return (unsigned short)((u + 0x7fffu + ((u >> 16) & 1u)) >> 16);
}
__device__ __forceinline__ float bf_lo(unsigned int w) { return __uint_as_float(w << 16); }
__device__ __forceinline__ float bf_hi(unsigned int w) { return __uint_as_float(w & 0xffff0000u); }

typedef __attribute__((address_space(3))) float lds_f;
typedef __attribute__((address_space(1))) const float glb_f;
__device__ __forceinline__ void gload16(const float* g, float* l) {
    __builtin_amdgcn_global_load_lds((glb_f*)g, (lds_f*)l, 16, 0, 0);
}

#define SCHED_FENCE() __builtin_amdgcn_sched_barrier(0)
#define WAIT_VM4()  asm volatile("s_waitcnt vmcnt(4)" ::: "memory")
#define WAIT_VM3()  asm volatile("s_waitcnt vmcnt(3)" ::: "memory")
#define WAIT_VM0()  asm volatile("s_waitcnt vmcnt(0)" ::: "memory")
#define WAIT_LGKM0() asm volatile("s_waitcnt lgkmcnt(0)" ::: "memory")

// ---------------------------------------------------------------------------
// K1: fused gather+GEMM1 (round-10 structure — best measured: 85.2 us total).
// grid = (64 images, KSEL=16), 256 thr, ~30 KB LDS -> 4 blocks/CU, LB(256,4).
// Slab = 4 channels (12.5 KB), counted-vmcnt 2-deep pipeline: per slab per
// wave w0 issues 3 VMEM, w1-3 issue 4; waits are literal vmcnt(3)/vmcnt(4).
// All acc indices compile-time (rule #20). Bucket scan overlaps slab-0/1 DMA.
// Writes Hp[ks][g][o] bf16 partials. nb<=128 assumed (P(nb>128) ~ 1e-9).
// ---------------------------------------------------------------------------
__global__ __launch_bounds__(256, 4) void k_fused(
    const float* __restrict__ F, const float* __restrict__ W1,
    const int* __restrict__ posi, const int* __restrict__ negi,
    unsigned short* __restrict__ Hp, int kchunk, int nslab)
{
    __shared__ float Pl[2][SLABF];     // 25088 B
    __shared__ float Wl[2][520];       //  4160 B (two 260-pitch halves)
    __shared__ int   pkl[128];
    __shared__ int   nbL;

    const int b    = blockIdx.x;
    const int ks   = blockIdx.y;
    const int t    = threadIdx.x;
    const int w    = t >> 6;
    const int lane = t & 63;

    if (t == 0) nbL = 0;
    if (t < 128) pkl[t] = 0;
    __syncthreads();                    // LDS init visible (no DMA yet)

    const int kb0 = ks * kchunk;

    auto issue = [&](int sl2, int buf) {
        const int kb = kb0 + sl2 * SLAB;
        const float* srcP = F + (size_t)b * FB + (size_t)kb * HW_;
        float* dstP = &Pl[buf][0];
#pragma unroll
        for (int i = 0; i < 3; ++i) {   // 12 chunks of 256 floats
            const int c = w + 4 * i;
            gload16(srcP + c * 256 + lane * 4, dstP + c * 256);
        }
        if (w == 3) {                   // tail 64 floats
            if (lane < 16) gload16(srcP + 3072 + lane * 4, dstP + 3072);
        }
        if (w == 1) gload16(W1 + (size_t)lane * CIN + kb, &Wl[buf][0]);
        if (w == 2) gload16(W1 + (size_t)(64 + lane) * CIN + kb, &Wl[buf][260]);
    };
    // per-wave VMEM count per slab: w0=3, w1..3=4

    // ---- issue slabs 0,1 FIRST; bucket scan overlaps the DMA
    issue(0, 0);
    issue(1, 1);

#pragma unroll
    for (int r = 0; r < 16; ++r) {
        const int g    = r * 256 + t;
        const int aidx = (g < NPOS) ? posi[g] : negi[g - NPOS];
        const int bb   = aidx / AHW;
        if (bb == b) {
            const int hw   = (aidx - bb * AHW) % HW_;
            const int slot = atomicAdd(&nbL, 1);
            if (slot < 128) pkl[slot] = (g << 10) | hw;
        }
    }
    WAIT_LGKM0();                       // own LDS atomics drained
    SCHED_FENCE();
    __builtin_amdgcn_s_barrier();       // bucket results visible
    SCHED_FENCE();

    const int  nb   = nbL;
    const bool wact = (w * 32) < nb;    // wave-uniform
    const int  og   = lane >> 3;        // 8 out-groups of 16 outs
    const int  al   = w * 32 + (lane & 7) * 4;  // first of this lane's 4 anchors
    int hwr[4], gr[4];
#pragma unroll
    for (int ai = 0; ai < 4; ++ai) {
        const int a  = al + ai;         // <= 127
        const int pk = pkl[a];
        hwr[ai] = pk & 1023;
        gr[ai]  = (a < nb) ? (pk >> 10) : -1;
    }
    const int WB = (og < 4) ? og * 64 : 260 + (og - 4) * 64;

    float acc[4][16];
#pragma unroll
    for (int ai = 0; ai < 4; ++ai)
#pragma unroll
        for (int m = 0; m < 16; ++m) acc[ai][m] = 0.0f;

    if (w == 0) { WAIT_VM3(); } else { WAIT_VM4(); }   // slab 0 arrived (own)
    SCHED_FENCE();
    __builtin_amdgcn_s_barrier();       // all waves' slab-0 loads arrived
    SCHED_FENCE();

    for (int sl = 0; sl < nslab; ++sl) {
        const int cur = sl & 1;
        if (wact) {
            float ga[4][4];
#pragma unroll
            for (int ai = 0; ai < 4; ++ai)
#pragma unroll
                for (int c = 0; c < 4; ++c)
                    ga[ai][c] = Pl[cur][c * HW_ + hwr[ai]];
#pragma unroll
            for (int m = 0; m < 16; ++m) {
                const float4 wv = *(const float4*)&Wl[cur][WB + 4 * m];
#pragma unroll
                for (int ai = 0; ai < 4; ++ai) {
                    float v = acc[ai][m];
                    v = fmaf(ga[ai][0], wv.x, v);
                    v = fmaf(ga[ai][1], wv.y, v);
                    v = fmaf(ga[ai][2], wv.z, v);
                    v = fmaf(ga[ai][3], wv.w, v);
                    acc[ai][m] = v;
                }
            }
        }
        if (sl + 1 < nslab) {
            WAIT_LGKM0();               // my reads of Pl[cur] complete
            SCHED_FENCE();
            __builtin_amdgcn_s_barrier();   // B1: everyone done with cur
            SCHED_FENCE();
            if (sl + 2 < nslab) {
                issue(sl + 2, cur);
                SCHED_FENCE();
                if (w == 0) { WAIT_VM3(); } else { WAIT_VM4(); }
            } else {
                WAIT_VM0();
            }
            SCHED_FENCE();
            __builtin_amdgcn_s_barrier();   // B2: slab sl+1 visible
            SCHED_FENCE();
        }
    }

    // ---- store bf16 partials: 4 anchors x 16 outs per lane (static pack)
    if (wact) {
#pragma unroll
        for (int ai = 0; ai < 4; ++ai) {
            const int g = gr[ai];
            if (g >= 0) {
                unsigned short* dst =
                    Hp + ((size_t)ks * NANCH + g) * HID + og * 16;
                unsigned u[8];
#pragma unroll
                for (int q = 0; q < 8; ++q)
                    u[q] = (unsigned)f2bf(acc[ai][2 * q]) |
                           ((unsigned)f2bf(acc[ai][2 * q + 1]) << 16);
                *(uint4*)(dst)     = make_uint4(u[0], u[1], u[2], u[3]);
                *(uint4*)(dst + 8) = make_uint4(u[4], u[5], u[6], u[7]);
            }
        }
    }
}

// ---------------------------------------------------------------------------
// K2: wave-per-anchor loss. Sums KSEL bf16 partials + bias + leaky inline,
// then layer-2 rows + IoU/argmax + losses. Plain store to contrib.
// ---------------------------------------------------------------------------
__global__ __launch_bounds__(256) void k_loss(
    const unsigned short* __restrict__ Hp, const float* __restrict__ b1,
    int ksel, const float* __restrict__ W2, const float* __restrict__ b2,
    const int* __restrict__ posi, const int* __restrict__ negi,
    const float* __restrict__ bboxes, const float* __restrict__ anc,
    float* __restrict__ contrib)
{
    const int wid  = threadIdx.x >> 6;
    const int lane = threadIdx.x & 63;
    const int g    = blockIdx.x * 4 + wid;

    const int aidx = (g < NPOS) ? posi[g] : negi[g - NPOS];
    const int b   = aidx / AHW;
    const int rem = aidx - b * AHW;
    const int a   = rem / HW_;
    const int hw  = rem - a * HW_;
    const int hh  = hw / W_;
    const int ww  = hw - hh * W_;

    float hx = b1[2 * lane], hy = b1[2 * lane + 1];
    for (int ks = 0; ks < ksel; ++ks) {
        const unsigned raw =
            *(const unsigned*)&Hp[((size_t)ks * NANCH + g) * HID + 2 * lane];
        hx += bf_lo(raw);
        hy += bf_hi(raw);
    }
    hx = (hx > 0.0f) ? hx : 0.01f * hx;
    hy = (hy > 0.0f) ? hy : 0.01f * hy;

    if (g < NPOS) {
        float outv[25];
#pragma unroll
        for (int j = 0; j < 25; ++j) {
            const int row = (j < 5) ? (5 * a + j) : (40 + j);
            const float2 w = *(const float2*)&W2[(size_t)row * HID + 2 * lane];
            float v = fmaf(w.x, hx, w.y * hy);
#pragma unroll
            for (int off = 1; off < 64; off <<= 1) v += __shfl_xor(v, off, 64);
            outv[j] = v + b2[row];
        }

        const float wa = anc[2 * a], ha = anc[2 * a + 1];
        const float cx = ww + 0.5f, cy = hh + 0.5f;
        const float ax1 = cx - 0.5f * wa, ay1 = cy - 0.5f * ha;
        const float ax2 = cx + 0.5f * wa, ay2 = cy + 0.5f * ha;
        const float areap = wa * ha;

        float v; int vi = lane;
        if (lane < 40) {
            const float* bb = &bboxes[(size_t)(b * 40 + lane) * 5];
            const float bx1 = bb[0], by1 = bb[1], bx2 = bb[2], by2 = bb[3];
            const float areab = (bx2 - bx1) * (by2 - by1);
            const float ix1 = fmaxf(ax1, bx1), iy1 = fmaxf(ay1, by1);
            const float ix2 = fminf(ax2, bx2), iy2 = fminf(ay2, by2);
            const float inter = fmaxf(ix2 - ix1, 0.0f) * fmaxf(iy2 - iy1, 0.0f);
            v = inter / (areap + areab - inter);
        } else {
            v = -1.0f;
        }
#pragma unroll
        for (int off = 1; off < 64; off <<= 1) {
            const float ov = __shfl_xor(v, off, 64);
            const int   oi = __shfl_xor(vi, off, 64);
            if (ov > v || (ov == v && oi < vi)) { v = ov; vi = oi; }
        }
        const int m = vi;

        const float* gt = &bboxes[(size_t)(b * 40 + m) * 5];
        const float gx1 = gt[0], gy1 = gt[1], gx2 = gt[2], gy2 = gt[3];
        const int   gcls = (int)gt[4];
        const float xb = 0.5f * (gx1 + gx2), yb = 0.5f * (gy1 + gy2);
        const float wb = gx2 - gx1, hb = gy2 - gy1;
        const float go0 = xb - cx, go1 = yb - cy;
        const float go2 = __logf(wb / wa), go3 = __logf(hb / ha);

        const float o0 = sigmoidf_(outv[1]) - 0.5f;
        const float o1 = sigmoidf_(outv[2]) - 0.5f;
        const float o2 = outv[3], o3 = outv[4];
        const float reg = (o0 - go0) * (o0 - go0) + (o1 - go1) * (o1 - go1) +
                          (o2 - go2) * (o2 - go2) + (o3 - go3) * (o3 - go3);

        const float conf = sigmoidf_(outv[0]);
        const float conft = (conf - 1.0f) * (conf - 1.0f);

        float mx = outv[5];
#pragma unroll
        for (int c = 1; c < 20; ++c) mx = fmaxf(mx, outv[5 + c]);
        float se = 0.0f;
#pragma unroll
        for (int c = 0; c < 20; ++c) se += __expf(outv[5 + c] - mx);
        float lgt = 0.0f;
#pragma unroll
        for (int c = 0; c < 20; ++c) if (c == gcls) lgt = outv[5 + c];
        const float clst = -(lgt - mx - __logf(se));

        if (lane == 0)
            contrib[g] = conft * (1.0f / 4096.0f) + reg * (1.0f / 2048.0f) +
                         clst * (1.0f / 2048.0f);
    } else {
        const int row = 5 * a;
        const float2 w = *(const float2*)&W2[(size_t)row * HID + 2 * lane];
        float v = fmaf(w.x, hx, w.y * hy);
#pragma unroll
        for (int off = 1; off < 64; off <<= 1) v += __shfl_xor(v, off, 64);
        const float conf = sigmoidf_(v + b2[row]);
        if (lane == 0) contrib[g] = conf * conf * (1.0f / 4096.0f);
    }
}

// ---------------------------------------------------------------------------
// K3: final reduction (deterministic)
// ---------------------------------------------------------------------------
__global__ __launch_bounds__(256) void k_final(const float* __restrict__ contrib,
                                               float* __restrict__ out)
{
    __shared__ float red[256];
    const int t = threadIdx.x;
    float s = 0.0f;
    for (int i = t; i < NANCH; i += 256) s += contrib[i];
    red[t] = s;
    __syncthreads();
    for (int st = 128; st > 0; st >>= 1) {
        if (t < st) red[t] += red[t + st];
        __syncthreads();
    }
    if (t == 0) out[0] = red[0];
}

extern "C" void kernel_launch(void* const* d_in, const int* in_sizes, int n_in,
                              void* d_out, int out_size, void* d_ws, size_t ws_size,
                              hipStream_t stream)
{
    const float* F      = (const float*)d_in[0];
    const float* bboxes = (const float*)d_in[1];
    const int*   posi   = (const int*)d_in[2];
    const int*   negi   = (const int*)d_in[3];
    const float* W1     = (const float*)d_in[4];
    const float* b1     = (const float*)d_in[5];
    const float* W2     = (const float*)d_in[6];
    const float* b2     = (const float*)d_in[7];
    const float* anc    = (const float*)d_in[8];
    float* out = (float*)d_out;

    char* ws = (char*)d_ws;
    int KSELr = 4;
    {
        const int opts[3] = {16, 8, 4};
        for (int i = 0; i < 3; ++i) {
            size_t need = (size_t)opts[i] * NANCH * HID * 2 + (size_t)NANCH * 4 + 256;
            if (need <= ws_size) { KSELr = opts[i]; break; }
        }
    }
    unsigned short* Hp      = (unsigned short*)ws;
    float*          contrib = (float*)(ws + (size_t)KSELr * NANCH * HID * 2);

    const int kchunk = CIN / KSELr;     // 80 (KSEL=16)
    const int nslab  = kchunk / SLAB;   // 20

    k_fused<<<dim3(64, KSELr), 256, 0, stream>>>(F, W1, posi, negi, Hp,
                                                 kchunk, nslab);
    k_loss<<<NANCH / 4, 256, 0, stream>>>(Hp, b1, KSELr, W2, b2, posi, negi,
                                          bboxes, anc, contrib);
    k_final<<<1, 256, 0, stream>>>(contrib, out);
    (void)in_sizes; (void)n_in; (void)out_size;
}